// Round 3
// baseline (701.410 us; speedup 1.0000x reference)
//
#include <hip/hip_runtime.h>
#include <stdint.h>

#define NN 128
#define BB 4096
#define HH 32

// Pre-pass: bit-pack A transposed into column masks.
// bitsW layout (as u64): index (b*128 + col)*2 + h, h=0 -> d 0..63, h=1 -> d 64..127.
// Thread (b, n4, h) owns columns 4*n4..4*n4+3 for d-range h*64..h*64+63.
// Wave reads 2 contiguous 512B segments per iteration (1 KiB/instr, fully coalesced).
__global__ __launch_bounds__(256) void pack_bits(const float* __restrict__ A,
                                                 unsigned long long* __restrict__ bitsW) {
    int t = blockIdx.x * 256 + threadIdx.x;   // BB*64 threads total
    int n4 = t & 31;
    int h  = (t >> 5) & 1;
    int b  = t >> 6;
    const float4* Ap = (const float4*)(A + (size_t)b * NN * NN + (size_t)h * 64 * NN) + n4;
    unsigned long long m0 = 0, m1 = 0, m2 = 0, m3 = 0;
#pragma unroll 8
    for (int d = 0; d < 64; ++d) {
        float4 v = Ap[(size_t)d * (NN / 4)];
        unsigned long long bit = 1ull << d;
        if (v.x != 0.f) m0 |= bit;
        if (v.y != 0.f) m1 |= bit;
        if (v.z != 0.f) m2 |= bit;
        if (v.w != 0.f) m3 |= bit;
    }
    unsigned long long* dst = bitsW + ((size_t)b * NN + n4 * 4) * 2 + h;
    dst[0] = m0; dst[2] = m1; dst[4] = m2; dst[6] = m3;
}

__device__ __forceinline__ float bcast_lane(float v, int lane) {
    return __uint_as_float(
        (unsigned)__builtin_amdgcn_readlane((int)__float_as_uint(v), lane));
}

// One wave (64 lanes) per batch element. outputs state: out0 (d=lane), out1 (d=lane+64).
// Sparse gather via wave-uniform scalar bit-walk: masks live in SGPRs, s_ff1 extracts
// indices, v_readlane broadcasts values — zero LDS, zero barriers.
__global__ __launch_bounds__(64) void cond_mlp(
    const float* __restrict__ x, const float* __restrict__ u,
    const float* __restrict__ W1, const float* __restrict__ b1,
    const float* __restrict__ W2, const float* __restrict__ b2,
    const int* __restrict__ order, const int* __restrict__ do_idxs,
    const ulonglong2* __restrict__ bitsT, float* __restrict__ out)
{
    const int b = blockIdx.x;
    const int lane = threadIdx.x;
    const int j = lane & 31;       // hidden index (halves duplicate)

    const float ub = u[b];
    const int dob = do_idxs[b];
    float out0 = (dob == lane) ? ub : 0.f;
    float out1 = (dob == lane + 64) ? ub : 0.f;

    const int* ord = order + b * NN;
    const ulonglong2* bb = bitsT + (size_t)b * NN;

    int node = ord[0];
    ulonglong2 bits = bb[node];

    for (int t = 0; t < NN; ++t) {
        // ---- prefetch next step's uniform data (scalar loads, in flight early) ----
        const int node_n = (t < NN - 1) ? ord[t + 1] : 0;
        const ulonglong2 bits_n = bb[node_n];

        const float* __restrict__ Wn = W1 + (size_t)node * (NN + 1) * HH;
        // epilogue operands issued before the gather so they're in flight
        const float w2v = W2[node * HH + j];
        const float b1v = b1[node * HH + j];
        const float wxv = Wn[NN * HH + j];      // x input row (row 128)
        const float xv  = x[b * NN + node];
        const float b2v = b2[node];

        // ---- wave-uniform masks (SGPR pairs) ----
        unsigned long long m0 = __ballot(out0 != 0.f) & bits.x;
        unsigned long long m1 = __ballot(out1 != 0.f) & bits.y;

        // ---- scalar bit-walk gather: dual stream, 2-unrolled, 4 loads in flight ----
        float acc0 = 0.f, acc1 = 0.f, acc2 = 0.f, acc3 = 0.f;
        while (m0 | m1) {
            if (m0) {
                int d0 = __builtin_ctzll(m0); m0 &= m0 - 1;
                int d1 = 0; float v1 = 0.f;
                if (m0) {
                    d1 = __builtin_ctzll(m0); m0 &= m0 - 1;
                    v1 = bcast_lane(out0, d1);
                }
                float v0 = bcast_lane(out0, d0);
                float w0 = Wn[d0 * HH + j];
                float w1 = Wn[d1 * HH + j];
                acc0 = fmaf(v0, w0, acc0);
                acc1 = fmaf(v1, w1, acc1);
            }
            if (m1) {
                int d0 = __builtin_ctzll(m1); m1 &= m1 - 1;
                int d1 = 0; float v1 = 0.f;
                if (m1) {
                    d1 = __builtin_ctzll(m1); m1 &= m1 - 1;
                    v1 = bcast_lane(out1, d1);
                }
                float v0 = bcast_lane(out1, d0);
                float w0 = Wn[(64 + d0) * HH + j];
                float w1 = Wn[(64 + d1) * HH + j];
                acc2 = fmaf(v0, w0, acc2);
                acc3 = fmaf(v1, w1, acc3);
            }
        }

        float acc = (acc0 + acc1) + (acc2 + acc3);   // halves hold identical sums
        acc = fmaf(xv, wxv, acc) + b1v;
        const float hv = fmaxf(acc, 0.01f * acc);    // leaky_relu

        float p = hv * w2v;                          // H -> 1 reduction within 32-halves
        p += __shfl_xor(p, 16);
        p += __shfl_xor(p, 8);
        p += __shfl_xor(p, 4);
        p += __shfl_xor(p, 2);
        p += __shfl_xor(p, 1);
        const float outv = p + b2v;                  // identical in all 64 lanes

        // ---- state update (skip if this is the do-intervention node) ----
        if (dob != node) {
            if (lane == (node & 63)) {
                if (node < 64) out0 = outv; else out1 = outv;
            }
        }
        node = node_n;
        bits = bits_n;
    }

    out[b * NN + lane] = out0;
    out[b * NN + 64 + lane] = out1;
}

extern "C" void kernel_launch(void* const* d_in, const int* in_sizes, int n_in,
                              void* d_out, int out_size, void* d_ws, size_t ws_size,
                              hipStream_t stream) {
    const float* x   = (const float*)d_in[0];
    const float* A   = (const float*)d_in[1];
    const float* u   = (const float*)d_in[2];
    const float* W1  = (const float*)d_in[3];
    const float* b1  = (const float*)d_in[4];
    const float* W2  = (const float*)d_in[5];
    const float* b2  = (const float*)d_in[6];
    const int* order = (const int*)d_in[7];
    const int* dox   = (const int*)d_in[8];

    unsigned long long* bitsW = (unsigned long long*)d_ws;  // 4096*128*16 B = 8 MB

    pack_bits<<<(BB * 64) / 256, 256, 0, stream>>>(A, bitsW);
    cond_mlp<<<BB, 64, 0, stream>>>(x, u, W1, b1, W2, b2, order, dox,
                                    (const ulonglong2*)bitsW, (float*)d_out);
}

// Round 4
// 663.472 us; speedup vs baseline: 1.0572x; 1.0572x over previous
//
#include <hip/hip_runtime.h>
#include <stdint.h>

#define NN 128
#define BB 4096
#define HH 32

// ---------------------------------------------------------------------------
// Pre-pass 1: bit-pack A transposed into column masks.
// bitsT[b*128+col] = {bits d=0..63, bits d=64..127}, bit d = (A[b][d][col]!=0)
// ---------------------------------------------------------------------------
__global__ __launch_bounds__(256) void pack_bits(const float* __restrict__ A,
                                                 unsigned long long* __restrict__ bitsW) {
    int t = blockIdx.x * 256 + threadIdx.x;   // BB*64 threads total
    int n4 = t & 31;
    int h  = (t >> 5) & 1;
    int b  = t >> 6;
    const float4* Ap = (const float4*)(A + (size_t)b * NN * NN + (size_t)h * 64 * NN) + n4;
    unsigned long long m0 = 0, m1 = 0, m2 = 0, m3 = 0;
#pragma unroll 8
    for (int d = 0; d < 64; ++d) {
        float4 v = Ap[(size_t)d * (NN / 4)];
        unsigned long long bit = 1ull << d;
        if (v.x != 0.f) m0 |= bit;
        if (v.y != 0.f) m1 |= bit;
        if (v.z != 0.f) m2 |= bit;
        if (v.w != 0.f) m3 |= bit;
    }
    unsigned long long* dst = bitsW + ((size_t)b * NN + n4 * 4) * 2 + h;
    dst[0] = m0; dst[2] = m1; dst[4] = m2; dst[6] = m3;
}

// ---------------------------------------------------------------------------
// Pre-pass 2: build per-(b,t) gather lists. Slot = 64 B:
//   byte0 = padded count (multiple of 4, <=60) or 255 (mask fallback)
//   byte1 = node_t;  bytes 4..63 = u8 entry indices (pad = 128)
//   fallback: bytes 8..23 = m0,m1 (u64 masks)
// One wave per batch element; lane handles t=lane and t=64+lane.
// P_t (available set) built via prefix-OR shuffle scan — value-independent!
// ---------------------------------------------------------------------------
__device__ __forceinline__ void fill_slot(uint8_t* s, int node,
                                          uint64_t m0, uint64_t m1) {
    int cnt = __popcll(m0) + __popcll(m1);
    s[1] = (uint8_t)node;
    if (cnt <= 60) {
        int c = 0;
        while (m0) { int d = __builtin_ctzll(m0); m0 &= m0 - 1; s[4 + c] = (uint8_t)d; ++c; }
        while (m1) { int d = __builtin_ctzll(m1); m1 &= m1 - 1; s[4 + c] = (uint8_t)(64 + d); ++c; }
        while (c & 3) { s[4 + c] = 128; ++c; }
        s[0] = (uint8_t)c;
    } else {
        s[0] = 255;
        *(uint64_t*)(s + 8)  = m0;
        *(uint64_t*)(s + 16) = m1;
    }
}

__global__ __launch_bounds__(256) void build_lists(
    const ulonglong2* __restrict__ bitsT, const int* __restrict__ order,
    const int* __restrict__ do_idxs, uint8_t* __restrict__ lists)
{
    __shared__ uint8_t slot[4][128][64];   // 32 KB
    const int wv = threadIdx.x >> 6, lane = threadIdx.x & 63;
    const int b = blockIdx.x * 4 + wv;
    const int na  = order[b * NN + lane];
    const int nb  = order[b * NN + 64 + lane];
    const int dob = do_idxs[b];

    uint64_t sa_lo = (na < 64) ? (1ull << na) : 0ull;
    uint64_t sa_hi = (na < 64) ? 0ull : (1ull << (na - 64));
    uint64_t sb_lo = (nb < 64) ? (1ull << nb) : 0ull;
    uint64_t sb_hi = (nb < 64) ? 0ull : (1ull << (nb - 64));
#pragma unroll
    for (int s = 1; s < 64; s <<= 1) {
        uint64_t t0 = __shfl_up(sa_lo, s), t1 = __shfl_up(sa_hi, s);
        uint64_t t2 = __shfl_up(sb_lo, s), t3 = __shfl_up(sb_hi, s);
        if (lane >= s) { sa_lo |= t0; sa_hi |= t1; sb_lo |= t2; sb_hi |= t3; }
    }
    uint64_t Pa_lo = __shfl_up(sa_lo, 1), Pa_hi = __shfl_up(sa_hi, 1);
    uint64_t Pb_lo = __shfl_up(sb_lo, 1), Pb_hi = __shfl_up(sb_hi, 1);
    if (lane == 0) { Pa_lo = 0; Pa_hi = 0; Pb_lo = 0; Pb_hi = 0; }
    const uint64_t f_lo = __shfl(sa_lo, 63), f_hi = __shfl(sa_hi, 63);
    Pb_lo |= f_lo; Pb_hi |= f_hi;
    if (dob >= 0) {
        uint64_t dlo = (dob < 64) ? (1ull << dob) : 0ull;
        uint64_t dhi = (dob < 64) ? 0ull : (1ull << (dob - 64));
        Pa_lo |= dlo; Pa_hi |= dhi; Pb_lo |= dlo; Pb_hi |= dhi;
    }
    const ulonglong2 ba = bitsT[(size_t)b * NN + na];
    const ulonglong2 bc = bitsT[(size_t)b * NN + nb];
    fill_slot(&slot[wv][lane][0],      na, Pa_lo & ba.x, Pa_hi & ba.y);
    fill_slot(&slot[wv][64 + lane][0], nb, Pb_lo & bc.x, Pb_hi & bc.y);
    __syncthreads();
    const int4* src = (const int4*)&slot[0][0][0];
    int4* dst = (int4*)(lists + (size_t)blockIdx.x * 32768);
    for (int i = threadIdx.x; i < 2048; i += 256) dst[i] = src[i];
}

// ---------------------------------------------------------------------------
// Main kernel: one wave per batch element. vals[] (current outputs) in LDS;
// per step: decode precomputed slot (SGPRs), straight-line gather via Duff
// switch (all W1 loads batched in flight), shfl reduce, one LDS write.
// ---------------------------------------------------------------------------
#define ENTB(w, sh) { int d = ((w) >> (sh)) & 255; \
    const float* rp = Wn + d * HH; \
    float wv = rp[j]; float vv = vals[d]; acc = fmaf(vv, wv, acc); }
#define CHUNK(w) ENTB(w, 0) ENTB(w, 8) ENTB(w, 16) ENTB(w, 24)

__global__ __launch_bounds__(64) void cond_mlp_list(
    const float* __restrict__ x, const float* __restrict__ u,
    const float* __restrict__ W1, const float* __restrict__ b1,
    const float* __restrict__ W2, const float* __restrict__ b2,
    const int* __restrict__ do_idxs, const uint8_t* __restrict__ lists,
    float* __restrict__ out)
{
    const int b = blockIdx.x;
    const int lane = threadIdx.x;
    const int j = lane & 31;

    __shared__ float vals[132];
    const int dob = do_idxs[b];
    const float ub = u[b];
    vals[lane]      = (lane == dob) ? ub : 0.f;
    vals[64 + lane] = (lane + 64 == dob) ? ub : 0.f;
    if (lane < 4) vals[128 + lane] = 0.f;
    __syncthreads();

    const uint32_t* sp = (const uint32_t*)(lists + (size_t)b * 8192);

    for (int t = 0; t < NN; ++t) {
        const uint32_t* s = sp + (t << 4);
        uint32_t h0 = s[0], h1 = s[1], h2 = s[2],  h3 = s[3];
        uint32_t h4 = s[4], h5 = s[5], h6 = s[6],  h7 = s[7];
        uint32_t h8 = s[8], h9 = s[9], h10 = s[10], h11 = s[11];
        uint32_t h12 = s[12], h13 = s[13], h14 = s[14], h15 = s[15];
        const int cnt  = h0 & 255;
        const int node = (h0 >> 8) & 255;

        const float* __restrict__ Wn = W1 + (size_t)node * (NN + 1) * HH;
        const float w2v = W2[node * HH + j];
        const float b1v = b1[node * HH + j];
        const float wxv = Wn[NN * HH + j];
        const float xv  = x[(b << 7) + node];
        const float b2v = b2[node];

        float acc = 0.f;
        if (cnt != 255) {
            switch (cnt >> 2) {
            case 15: CHUNK(h15); case 14: CHUNK(h14); case 13: CHUNK(h13);
            case 12: CHUNK(h12); case 11: CHUNK(h11); case 10: CHUNK(h10);
            case 9:  CHUNK(h9);  case 8:  CHUNK(h8);  case 7:  CHUNK(h7);
            case 6:  CHUNK(h6);  case 5:  CHUNK(h5);  case 4:  CHUNK(h4);
            case 3:  CHUNK(h3);  case 2:  CHUNK(h2);  case 1:  CHUNK(h1);
            case 0:  ;
            }
        } else {
            uint64_t m0 = ((uint64_t)h3 << 32) | h2;
            uint64_t m1 = ((uint64_t)h5 << 32) | h4;
            while (m0) { int d = __builtin_ctzll(m0); m0 &= m0 - 1;
                         acc = fmaf(vals[d], Wn[d * HH + j], acc); }
            while (m1) { int d = __builtin_ctzll(m1); m1 &= m1 - 1;
                         acc = fmaf(vals[64 + d], Wn[(64 + d) * HH + j], acc); }
        }

        acc = fmaf(xv, wxv, acc) + b1v;
        const float hv = fmaxf(acc, 0.01f * acc);     // leaky_relu

        float p = hv * w2v;
        p += __shfl_xor(p, 16);
        p += __shfl_xor(p, 8);
        p += __shfl_xor(p, 4);
        p += __shfl_xor(p, 2);
        p += __shfl_xor(p, 1);
        const float outv = p + b2v;                   // uniform in each half; both halves identical

        if (node != dob) {
            if (lane == 0) vals[node] = outv;
        }
    }

    out[b * NN + lane]      = vals[lane];
    out[b * NN + 64 + lane] = vals[64 + lane];
}

// ---------------------------------------------------------------------------
// Fallback main kernel (R1, known-good, needs only the 8 MB bit buffer) —
// used only if ws_size can't hold the list buffer.
// ---------------------------------------------------------------------------
__global__ __launch_bounds__(64) void cond_mlp_ballot(
    const float* __restrict__ x, const float* __restrict__ u,
    const float* __restrict__ W1, const float* __restrict__ b1,
    const float* __restrict__ W2, const float* __restrict__ b2,
    const int* __restrict__ order, const int* __restrict__ do_idxs,
    const ulonglong2* __restrict__ bitsT, float* __restrict__ out)
{
    const int b = blockIdx.x;
    const int lane = threadIdx.x;
    const int j = lane & 31;
    const int half = lane >> 5;

    __shared__ float2 ent[132];

    const float ub = u[b];
    const int dob = do_idxs[b];
    float out0 = (dob == lane) ? ub : 0.f;
    float out1 = (dob == lane + 64) ? ub : 0.f;

    const int* ord = order + b * NN;
    const ulonglong2* bb = bitsT + (size_t)b * NN;

    int node = ord[0];
    ulonglong2 bits = bb[node];

    for (int t = 0; t < NN; ++t) {
        const int node_n = (t < NN - 1) ? ord[t + 1] : 0;
        const ulonglong2 bits_n = bb[node_n];

        const float* Wn = W1 + (size_t)node * (NN + 1) * HH;
        const float w2v = W2[node * HH + j];
        const float b1v = b1[node * HH + j];
        const float xv  = x[b * NN + node];
        const float b2v = b2[node];

        unsigned long long bal0 = __ballot(out0 != 0.f) & bits.x;
        unsigned long long bal1 = __ballot(out1 != 0.f) & bits.y;
        const int c0 = __popcll(bal0);
        const int cnt = c0 + __popcll(bal1);
        const unsigned long long below = (1ull << lane) - 1;
        if (bal0 & (1ull << lane)) {
            int p = __popcll(bal0 & below);
            ent[p] = make_float2(out0, __int_as_float(lane));
        }
        if (bal1 & (1ull << lane)) {
            int p = c0 + __popcll(bal1 & below);
            ent[p] = make_float2(out1, __int_as_float(lane + 64));
        }
        const int cnt4 = (cnt + 3) & ~3;
        if (lane < cnt4 - cnt) ent[cnt + lane] = make_float2(0.f, __int_as_float(0));
        __syncthreads();

        float acc0 = 0.f, acc1 = 0.f;
        for (int k = 0; k < cnt4; k += 4) {
            float2 eA = ent[k + half];
            float2 eB = ent[k + 2 + half];
            acc0 += eA.x * Wn[__float_as_int(eA.y) * HH + j];
            acc1 += eB.x * Wn[__float_as_int(eB.y) * HH + j];
        }
        __syncthreads();

        float acc = acc0 + acc1;
        acc += __shfl_xor(acc, 32);
        acc += xv * Wn[NN * HH + j];
        acc += b1v;
        const float hv = (acc > 0.f) ? acc : 0.01f * acc;

        float p = hv * w2v;
        p += __shfl_xor(p, 16);
        p += __shfl_xor(p, 8);
        p += __shfl_xor(p, 4);
        p += __shfl_xor(p, 2);
        p += __shfl_xor(p, 1);
        const float outv = p + b2v;

        if (dob != node) {
            if (lane == (node & 63)) {
                if (node < 64) out0 = outv; else out1 = outv;
            }
        }
        node = node_n;
        bits = bits_n;
    }

    out[b * NN + lane] = out0;
    out[b * NN + 64 + lane] = out1;
}

extern "C" void kernel_launch(void* const* d_in, const int* in_sizes, int n_in,
                              void* d_out, int out_size, void* d_ws, size_t ws_size,
                              hipStream_t stream) {
    const float* x   = (const float*)d_in[0];
    const float* A   = (const float*)d_in[1];
    const float* u   = (const float*)d_in[2];
    const float* W1  = (const float*)d_in[3];
    const float* b1  = (const float*)d_in[4];
    const float* W2  = (const float*)d_in[5];
    const float* b2  = (const float*)d_in[6];
    const int* order = (const int*)d_in[7];
    const int* dox   = (const int*)d_in[8];

    unsigned long long* bitsW = (unsigned long long*)d_ws;      // 8 MB
    uint8_t* lists = (uint8_t*)d_ws + (size_t)8 * 1024 * 1024;  // 33.5 MB
    const size_t need = (size_t)8 * 1024 * 1024 + (size_t)BB * NN * 64;

    pack_bits<<<(BB * 64) / 256, 256, 0, stream>>>(A, bitsW);
    if (ws_size >= need) {
        build_lists<<<BB / 4, 256, 0, stream>>>((const ulonglong2*)bitsW, order, dox, lists);
        cond_mlp_list<<<BB, 64, 0, stream>>>(x, u, W1, b1, W2, b2, dox, lists, (float*)d_out);
    } else {
        cond_mlp_ballot<<<BB, 64, 0, stream>>>(x, u, W1, b1, W2, b2, order, dox,
                                               (const ulonglong2*)bitsW, (float*)d_out);
    }
}

// Round 5
// 565.222 us; speedup vs baseline: 1.2409x; 1.1738x over previous
//
#include <hip/hip_runtime.h>
#include <stdint.h>

#define NN 128
#define BB 4096
#define HH 32
#define SLOT_W 17               // words per slot (68 B stride; 64 B payload)
#define BATCH_W (NN * SLOT_W)   // 2176 words per batch

// ---------------------------------------------------------------------------
// Pre-pass 1: bit-pack A transposed into column masks.
// bitsT[b*128+col] = {bits d=0..63, bits d=64..127}, bit d = (A[b][d][col]!=0)
// ---------------------------------------------------------------------------
__global__ __launch_bounds__(256) void pack_bits(const float* __restrict__ A,
                                                 unsigned long long* __restrict__ bitsW) {
    int t = blockIdx.x * 256 + threadIdx.x;   // BB*64 threads total
    int n4 = t & 31;
    int h  = (t >> 5) & 1;
    int b  = t >> 6;
    const float4* Ap = (const float4*)(A + (size_t)b * NN * NN + (size_t)h * 64 * NN) + n4;
    unsigned long long m0 = 0, m1 = 0, m2 = 0, m3 = 0;
#pragma unroll 8
    for (int d = 0; d < 64; ++d) {
        float4 v = Ap[(size_t)d * (NN / 4)];
        unsigned long long bit = 1ull << d;
        if (v.x != 0.f) m0 |= bit;
        if (v.y != 0.f) m1 |= bit;
        if (v.z != 0.f) m2 |= bit;
        if (v.w != 0.f) m3 |= bit;
    }
    unsigned long long* dst = bitsW + ((size_t)b * NN + n4 * 4) * 2 + h;
    dst[0] = m0; dst[2] = m1; dst[4] = m2; dst[6] = m3;
}

// ---------------------------------------------------------------------------
// Pre-pass 2: per-(b,t) gather slots, 64B payload / 68B stride:
//   byte0 = padded count (x8, <=56) or 255 (mask fallback)
//   byte1 = node_t
//   bytes 8..63 = u8 entry indices (pad = 128)
//   fallback: bytes 8..23 = m0,m1 as 4x u32
// ---------------------------------------------------------------------------
__device__ __forceinline__ void fill_slot(uint8_t* s, int node,
                                          uint64_t m0, uint64_t m1) {
    int cnt = __popcll(m0) + __popcll(m1);
    s[1] = (uint8_t)node;
    if (cnt <= 56) {
        int c = 0;
        while (m0) { int d = __builtin_ctzll(m0); m0 &= m0 - 1; s[8 + c] = (uint8_t)d; ++c; }
        while (m1) { int d = __builtin_ctzll(m1); m1 &= m1 - 1; s[8 + c] = (uint8_t)(64 + d); ++c; }
        while (c & 7) { s[8 + c] = 128; ++c; }
        s[0] = (uint8_t)c;
    } else {
        s[0] = 255;
        uint32_t* mp = (uint32_t*)(s + 8);
        mp[0] = (uint32_t)m0; mp[1] = (uint32_t)(m0 >> 32);
        mp[2] = (uint32_t)m1; mp[3] = (uint32_t)(m1 >> 32);
    }
}

__global__ __launch_bounds__(256) void build_lists(
    const ulonglong2* __restrict__ bitsT, const int* __restrict__ order,
    const int* __restrict__ do_idxs, uint32_t* __restrict__ lists)
{
    __shared__ uint8_t slot[4][NN][68];   // 34816 B; 17-word stride -> conflict-free
    const int wv = threadIdx.x >> 6, lane = threadIdx.x & 63;
    const int b = blockIdx.x * 4 + wv;
    const int na  = order[b * NN + lane];
    const int nb  = order[b * NN + 64 + lane];
    const int dob = do_idxs[b];

    uint64_t sa_lo = (na < 64) ? (1ull << na) : 0ull;
    uint64_t sa_hi = (na < 64) ? 0ull : (1ull << (na - 64));
    uint64_t sb_lo = (nb < 64) ? (1ull << nb) : 0ull;
    uint64_t sb_hi = (nb < 64) ? 0ull : (1ull << (nb - 64));
#pragma unroll
    for (int s = 1; s < 64; s <<= 1) {
        uint64_t t0 = __shfl_up(sa_lo, s), t1 = __shfl_up(sa_hi, s);
        uint64_t t2 = __shfl_up(sb_lo, s), t3 = __shfl_up(sb_hi, s);
        if (lane >= s) { sa_lo |= t0; sa_hi |= t1; sb_lo |= t2; sb_hi |= t3; }
    }
    uint64_t Pa_lo = __shfl_up(sa_lo, 1), Pa_hi = __shfl_up(sa_hi, 1);
    uint64_t Pb_lo = __shfl_up(sb_lo, 1), Pb_hi = __shfl_up(sb_hi, 1);
    if (lane == 0) { Pa_lo = 0; Pa_hi = 0; Pb_lo = 0; Pb_hi = 0; }
    const uint64_t f_lo = __shfl(sa_lo, 63), f_hi = __shfl(sa_hi, 63);
    Pb_lo |= f_lo; Pb_hi |= f_hi;
    if (dob >= 0) {
        uint64_t dlo = (dob < 64) ? (1ull << dob) : 0ull;
        uint64_t dhi = (dob < 64) ? 0ull : (1ull << (dob - 64));
        Pa_lo |= dlo; Pa_hi |= dhi; Pb_lo |= dlo; Pb_hi |= dhi;
    }
    const ulonglong2 ba = bitsT[(size_t)b * NN + na];
    const ulonglong2 bc = bitsT[(size_t)b * NN + nb];
    fill_slot(&slot[wv][lane][0],      na, Pa_lo & ba.x, Pa_hi & ba.y);
    fill_slot(&slot[wv][64 + lane][0], nb, Pb_lo & bc.x, Pb_hi & bc.y);
    __syncthreads();
    const uint32_t* src = (const uint32_t*)&slot[0][0][0];
    uint32_t* dst = lists + (size_t)blockIdx.x * (4 * BATCH_W);
    for (int i = threadIdx.x; i < 4 * BATCH_W; i += 256) dst[i] = src[i];
}

// ---------------------------------------------------------------------------
// Main kernel: one wave per batch. Slot t distributed across lanes (1 VGPR),
// prefetched one step ahead; ds_bpermute extracts per-lane entry index;
// 8 rows per global_load_dwordx4 (1024B/instr); all gather iters independent.
// Only the vals[node] LDS write->read is on the cross-step critical path.
// ---------------------------------------------------------------------------
#define ENT8(k) { \
    uint32_t wb = (uint32_t)__builtin_amdgcn_ds_bpermute(baddr + ((k) << 3), (int)sv); \
    int d = (wb >> sh2) & 255; \
    float vv = vals[d]; \
    const float4 wr = *(const float4*)(Wp + (d << 5)); \
    acc.x = fmaf(vv, wr.x, acc.x); acc.y = fmaf(vv, wr.y, acc.y); \
    acc.z = fmaf(vv, wr.z, acc.z); acc.w = fmaf(vv, wr.w, acc.w); }

__global__ __launch_bounds__(64) void cond_mlp_list(
    const float* __restrict__ x, const float* __restrict__ u,
    const float* __restrict__ W1, const float* __restrict__ b1,
    const float* __restrict__ W2, const float* __restrict__ b2,
    const int* __restrict__ do_idxs, const uint32_t* __restrict__ lists,
    float* __restrict__ out)
{
    const int b = blockIdx.x;
    const int lane = threadIdx.x;
    const int jj = (lane & 7) << 2;               // h-quad base (float index)
    const int sh2 = lane & 24;                    // 8*((lane>>3)&3)
    const int baddr = (2 + (lane >> 5)) << 2;     // bpermute byte addr base
    const int q = lane >> 3;                      // entry-group id 0..7

    __shared__ float vals[132];
    const int dob = do_idxs[b];
    const float ub = u[b];
    vals[lane]      = (lane == dob) ? ub : 0.f;
    vals[64 + lane] = (lane + 64 == dob) ? ub : 0.f;
    if (lane < 4) vals[128 + lane] = 0.f;

    const uint32_t* sp = lists + (size_t)b * BATCH_W;
    uint32_t sv = sp[lane & 15];                  // slot 0, distributed

    for (int t = 0; t < NN; ++t) {
        const int tn = (t < NN - 1) ? t + 1 : t;
        const uint32_t sv_n = sp[tn * SLOT_W + (lane & 15)];   // prefetch next slot

        const uint32_t w0 = (uint32_t)__builtin_amdgcn_readfirstlane((int)sv);
        const int cnt  = w0 & 255;
        const int node = (w0 >> 8) & 255;

        const float* __restrict__ Wp = W1 + (size_t)node * ((NN + 1) * HH) + jj;
        const float4 wx  = *(const float4*)(Wp + NN * HH);
        const float4 b1q = *(const float4*)(b1 + (node << 5) + jj);
        const float4 w2q = *(const float4*)(W2 + (node << 5) + jj);
        const float  xv  = x[(b << 7) + node];
        const float  b2v = b2[node];

        float4 acc = make_float4(0.f, 0.f, 0.f, 0.f);
        if (cnt != 255) {
            switch (cnt >> 3) {
            case 7: ENT8(6); case 6: ENT8(5); case 5: ENT8(4);
            case 4: ENT8(3); case 3: ENT8(2); case 2: ENT8(1);
            case 1: ENT8(0); case 0: ;
            }
        } else {
            // rare (>56 entries) mask-walk fallback
            uint32_t mw0 = (uint32_t)__builtin_amdgcn_readlane((int)sv, 2);
            uint32_t mw1 = (uint32_t)__builtin_amdgcn_readlane((int)sv, 3);
            uint32_t mw2 = (uint32_t)__builtin_amdgcn_readlane((int)sv, 4);
            uint32_t mw3 = (uint32_t)__builtin_amdgcn_readlane((int)sv, 5);
            uint64_t m0 = mw0 | ((uint64_t)mw1 << 32);
            uint64_t m1 = mw2 | ((uint64_t)mw3 << 32);
            int i = 0;
            while (m0) {
                int d = __builtin_ctzll(m0); m0 &= m0 - 1;
                float vv = ((i & 7) == q) ? vals[d] : 0.f;
                const float4 wr = *(const float4*)(Wp + (d << 5));
                acc.x = fmaf(vv, wr.x, acc.x); acc.y = fmaf(vv, wr.y, acc.y);
                acc.z = fmaf(vv, wr.z, acc.z); acc.w = fmaf(vv, wr.w, acc.w);
                ++i;
            }
            while (m1) {
                int d = 64 + __builtin_ctzll(m1); m1 &= m1 - 1;
                float vv = ((i & 7) == q) ? vals[d] : 0.f;
                const float4 wr = *(const float4*)(Wp + (d << 5));
                acc.x = fmaf(vv, wr.x, acc.x); acc.y = fmaf(vv, wr.y, acc.y);
                acc.z = fmaf(vv, wr.z, acc.z); acc.w = fmaf(vv, wr.w, acc.w);
                ++i;
            }
        }

        // fold the 8 entry-groups (bits 5,4,3 of lane)
        acc.x += __shfl_xor(acc.x, 32); acc.y += __shfl_xor(acc.y, 32);
        acc.z += __shfl_xor(acc.z, 32); acc.w += __shfl_xor(acc.w, 32);
        acc.x += __shfl_xor(acc.x, 16); acc.y += __shfl_xor(acc.y, 16);
        acc.z += __shfl_xor(acc.z, 16); acc.w += __shfl_xor(acc.w, 16);
        acc.x += __shfl_xor(acc.x, 8);  acc.y += __shfl_xor(acc.y, 8);
        acc.z += __shfl_xor(acc.z, 8);  acc.w += __shfl_xor(acc.w, 8);

        acc.x = fmaf(xv, wx.x, acc.x) + b1q.x;
        acc.y = fmaf(xv, wx.y, acc.y) + b1q.y;
        acc.z = fmaf(xv, wx.z, acc.z) + b1q.z;
        acc.w = fmaf(xv, wx.w, acc.w) + b1q.w;

        float4 h;
        h.x = fmaxf(acc.x, 0.01f * acc.x);
        h.y = fmaxf(acc.y, 0.01f * acc.y);
        h.z = fmaxf(acc.z, 0.01f * acc.z);
        h.w = fmaxf(acc.w, 0.01f * acc.w);

        float p = h.x * w2q.x + h.y * w2q.y + h.z * w2q.z + h.w * w2q.w;
        p += __shfl_xor(p, 4);
        p += __shfl_xor(p, 2);
        p += __shfl_xor(p, 1);
        const float outv = p + b2v;     // identical in all 64 lanes

        if (node != dob) {
            if (lane == 0) vals[node] = outv;
        }
        sv = sv_n;
    }

    out[(b << 7) + lane]      = vals[lane];
    out[(b << 7) + 64 + lane] = vals[64 + lane];
}

// ---------------------------------------------------------------------------
// Fallback (R1 ballot kernel) if ws too small for the lists buffer.
// ---------------------------------------------------------------------------
__global__ __launch_bounds__(64) void cond_mlp_ballot(
    const float* __restrict__ x, const float* __restrict__ u,
    const float* __restrict__ W1, const float* __restrict__ b1,
    const float* __restrict__ W2, const float* __restrict__ b2,
    const int* __restrict__ order, const int* __restrict__ do_idxs,
    const ulonglong2* __restrict__ bitsT, float* __restrict__ out)
{
    const int b = blockIdx.x;
    const int lane = threadIdx.x;
    const int j = lane & 31;
    const int half = lane >> 5;

    __shared__ float2 ent[132];

    const float ub = u[b];
    const int dob = do_idxs[b];
    float out0 = (dob == lane) ? ub : 0.f;
    float out1 = (dob == lane + 64) ? ub : 0.f;

    const int* ord = order + b * NN;
    const ulonglong2* bb = bitsT + (size_t)b * NN;

    int node = ord[0];
    ulonglong2 bits = bb[node];

    for (int t = 0; t < NN; ++t) {
        const int node_n = (t < NN - 1) ? ord[t + 1] : 0;
        const ulonglong2 bits_n = bb[node_n];

        const float* Wn = W1 + (size_t)node * (NN + 1) * HH;
        const float w2v = W2[node * HH + j];
        const float b1v = b1[node * HH + j];
        const float xv  = x[b * NN + node];
        const float b2v = b2[node];

        unsigned long long bal0 = __ballot(out0 != 0.f) & bits.x;
        unsigned long long bal1 = __ballot(out1 != 0.f) & bits.y;
        const int c0 = __popcll(bal0);
        const int cnt = c0 + __popcll(bal1);
        const unsigned long long below = (1ull << lane) - 1;
        if (bal0 & (1ull << lane)) {
            int p = __popcll(bal0 & below);
            ent[p] = make_float2(out0, __int_as_float(lane));
        }
        if (bal1 & (1ull << lane)) {
            int p = c0 + __popcll(bal1 & below);
            ent[p] = make_float2(out1, __int_as_float(lane + 64));
        }
        const int cnt4 = (cnt + 3) & ~3;
        if (lane < cnt4 - cnt) ent[cnt + lane] = make_float2(0.f, __int_as_float(0));
        __syncthreads();

        float acc0 = 0.f, acc1 = 0.f;
        for (int k = 0; k < cnt4; k += 4) {
            float2 eA = ent[k + half];
            float2 eB = ent[k + 2 + half];
            acc0 += eA.x * Wn[__float_as_int(eA.y) * HH + j];
            acc1 += eB.x * Wn[__float_as_int(eB.y) * HH + j];
        }
        __syncthreads();

        float acc = acc0 + acc1;
        acc += __shfl_xor(acc, 32);
        acc += xv * Wn[NN * HH + j];
        acc += b1v;
        const float hv = (acc > 0.f) ? acc : 0.01f * acc;

        float p = hv * w2v;
        p += __shfl_xor(p, 16);
        p += __shfl_xor(p, 8);
        p += __shfl_xor(p, 4);
        p += __shfl_xor(p, 2);
        p += __shfl_xor(p, 1);
        const float outv = p + b2v;

        if (dob != node) {
            if (lane == (node & 63)) {
                if (node < 64) out0 = outv; else out1 = outv;
            }
        }
        node = node_n;
        bits = bits_n;
    }

    out[b * NN + lane] = out0;
    out[b * NN + 64 + lane] = out1;
}

extern "C" void kernel_launch(void* const* d_in, const int* in_sizes, int n_in,
                              void* d_out, int out_size, void* d_ws, size_t ws_size,
                              hipStream_t stream) {
    const float* x   = (const float*)d_in[0];
    const float* A   = (const float*)d_in[1];
    const float* u   = (const float*)d_in[2];
    const float* W1  = (const float*)d_in[3];
    const float* b1  = (const float*)d_in[4];
    const float* W2  = (const float*)d_in[5];
    const float* b2  = (const float*)d_in[6];
    const int* order = (const int*)d_in[7];
    const int* dox   = (const int*)d_in[8];

    unsigned long long* bitsW = (unsigned long long*)d_ws;        // 8 MB
    uint32_t* lists = (uint32_t*)((uint8_t*)d_ws + (size_t)8 * 1024 * 1024);
    const size_t need = (size_t)8 * 1024 * 1024 + (size_t)BB * NN * 68;  // ~44 MB

    pack_bits<<<(BB * 64) / 256, 256, 0, stream>>>(A, bitsW);
    if (ws_size >= need) {
        build_lists<<<BB / 4, 256, 0, stream>>>((const ulonglong2*)bitsW, order, dox, lists);
        cond_mlp_list<<<BB, 64, 0, stream>>>(x, u, W1, b1, W2, b2, dox, lists, (float*)d_out);
    } else {
        cond_mlp_ballot<<<BB, 64, 0, stream>>>(x, u, W1, b1, W2, b2, order, dox,
                                               (const ulonglong2*)bitsW, (float*)d_out);
    }
}

// Round 6
// 547.291 us; speedup vs baseline: 1.2816x; 1.0328x over previous
//
#include <hip/hip_runtime.h>
#include <stdint.h>

#define NN 128
#define BB 4096
#define HH 32
#define SLOT_W 17               // words per slot (68 B stride; 64 B payload)
#define BATCH_W (NN * SLOT_W)   // 2176 words per batch

// ---------------------------------------------------------------------------
// Pre-pass 1: bit-pack A transposed into column masks.
// bitsT[b*128+col] = {bits d=0..63, bits d=64..127}, bit d = (A[b][d][col]!=0)
// ---------------------------------------------------------------------------
__global__ __launch_bounds__(256) void pack_bits(const float* __restrict__ A,
                                                 unsigned long long* __restrict__ bitsW) {
    int t = blockIdx.x * 256 + threadIdx.x;   // BB*64 threads total
    int n4 = t & 31;
    int h  = (t >> 5) & 1;
    int b  = t >> 6;
    const float4* Ap = (const float4*)(A + (size_t)b * NN * NN + (size_t)h * 64 * NN) + n4;
    unsigned long long m0 = 0, m1 = 0, m2 = 0, m3 = 0;
#pragma unroll 8
    for (int d = 0; d < 64; ++d) {
        float4 v = Ap[(size_t)d * (NN / 4)];
        unsigned long long bit = 1ull << d;
        if (v.x != 0.f) m0 |= bit;
        if (v.y != 0.f) m1 |= bit;
        if (v.z != 0.f) m2 |= bit;
        if (v.w != 0.f) m3 |= bit;
    }
    unsigned long long* dst = bitsW + ((size_t)b * NN + n4 * 4) * 2 + h;
    dst[0] = m0; dst[2] = m1; dst[4] = m2; dst[6] = m3;
}

// ---------------------------------------------------------------------------
// Pre-pass 2: per-(b,t) gather slots, 64B payload / 68B stride:
//   byte0 = padded count (x8, <=56) or 255 (mask fallback)
//   byte1 = node_t
//   bytes 8..63 = u8 entry indices (pad = 128)
//   fallback: bytes 8..23 = m0,m1 as 4x u32
// ---------------------------------------------------------------------------
__device__ __forceinline__ void fill_slot(uint8_t* s, int node,
                                          uint64_t m0, uint64_t m1) {
    int cnt = __popcll(m0) + __popcll(m1);
    s[1] = (uint8_t)node;
    if (cnt <= 56) {
        int c = 0;
        while (m0) { int d = __builtin_ctzll(m0); m0 &= m0 - 1; s[8 + c] = (uint8_t)d; ++c; }
        while (m1) { int d = __builtin_ctzll(m1); m1 &= m1 - 1; s[8 + c] = (uint8_t)(64 + d); ++c; }
        while (c & 7) { s[8 + c] = 128; ++c; }
        s[0] = (uint8_t)c;
    } else {
        s[0] = 255;
        uint32_t* mp = (uint32_t*)(s + 8);
        mp[0] = (uint32_t)m0; mp[1] = (uint32_t)(m0 >> 32);
        mp[2] = (uint32_t)m1; mp[3] = (uint32_t)(m1 >> 32);
    }
}

__global__ __launch_bounds__(256) void build_lists(
    const ulonglong2* __restrict__ bitsT, const int* __restrict__ order,
    const int* __restrict__ do_idxs, uint32_t* __restrict__ lists)
{
    __shared__ uint8_t slot[4][NN][68];   // 34816 B; 17-word stride -> conflict-free
    const int wv = threadIdx.x >> 6, lane = threadIdx.x & 63;
    const int b = blockIdx.x * 4 + wv;
    const int na  = order[b * NN + lane];
    const int nb  = order[b * NN + 64 + lane];
    const int dob = do_idxs[b];

    uint64_t sa_lo = (na < 64) ? (1ull << na) : 0ull;
    uint64_t sa_hi = (na < 64) ? 0ull : (1ull << (na - 64));
    uint64_t sb_lo = (nb < 64) ? (1ull << nb) : 0ull;
    uint64_t sb_hi = (nb < 64) ? 0ull : (1ull << (nb - 64));
#pragma unroll
    for (int s = 1; s < 64; s <<= 1) {
        uint64_t t0 = __shfl_up(sa_lo, s), t1 = __shfl_up(sa_hi, s);
        uint64_t t2 = __shfl_up(sb_lo, s), t3 = __shfl_up(sb_hi, s);
        if (lane >= s) { sa_lo |= t0; sa_hi |= t1; sb_lo |= t2; sb_hi |= t3; }
    }
    uint64_t Pa_lo = __shfl_up(sa_lo, 1), Pa_hi = __shfl_up(sa_hi, 1);
    uint64_t Pb_lo = __shfl_up(sb_lo, 1), Pb_hi = __shfl_up(sb_hi, 1);
    if (lane == 0) { Pa_lo = 0; Pa_hi = 0; Pb_lo = 0; Pb_hi = 0; }
    const uint64_t f_lo = __shfl(sa_lo, 63), f_hi = __shfl(sa_hi, 63);
    Pb_lo |= f_lo; Pb_hi |= f_hi;
    if (dob >= 0) {
        uint64_t dlo = (dob < 64) ? (1ull << dob) : 0ull;
        uint64_t dhi = (dob < 64) ? 0ull : (1ull << (dob - 64));
        Pa_lo |= dlo; Pa_hi |= dhi; Pb_lo |= dlo; Pb_hi |= dhi;
    }
    const ulonglong2 ba = bitsT[(size_t)b * NN + na];
    const ulonglong2 bc = bitsT[(size_t)b * NN + nb];
    fill_slot(&slot[wv][lane][0],      na, Pa_lo & ba.x, Pa_hi & ba.y);
    fill_slot(&slot[wv][64 + lane][0], nb, Pb_lo & bc.x, Pb_hi & bc.y);
    __syncthreads();
    const uint32_t* src = (const uint32_t*)&slot[0][0][0];
    uint32_t* dst = lists + (size_t)blockIdx.x * (4 * BATCH_W);
    for (int i = threadIdx.x; i < 4 * BATCH_W; i += 256) dst[i] = src[i];
}

// ---------------------------------------------------------------------------
// DPP-based cross-lane adds (VALU pipe, ~10 cyc vs ~120 for ds_swizzle)
// ---------------------------------------------------------------------------
__device__ __forceinline__ float dppadd_xor1(float v) {   // quad_perm [1,0,3,2]
    int t = __builtin_amdgcn_update_dpp(0, __float_as_int(v), 0xB1, 0xF, 0xF, true);
    return v + __int_as_float(t);
}
__device__ __forceinline__ float dppadd_xor2(float v) {   // quad_perm [2,3,0,1]
    int t = __builtin_amdgcn_update_dpp(0, __float_as_int(v), 0x4E, 0xF, 0xF, true);
    return v + __int_as_float(t);
}
__device__ __forceinline__ float dppadd_xor4(float v) {   // row_half_mirror (valid after xor1+xor2)
    int t = __builtin_amdgcn_update_dpp(0, __float_as_int(v), 0x141, 0xF, 0xF, true);
    return v + __int_as_float(t);
}
__device__ __forceinline__ float dppadd_xor8(float v) {   // row_ror:8 == xor8 within 16
    int t = __builtin_amdgcn_update_dpp(0, __float_as_int(v), 0x128, 0xF, 0xF, true);
    return v + __int_as_float(t);
}

// ---------------------------------------------------------------------------
// Main kernel: one wave per batch, 2-step software pipeline.
// PREF(stage, slot): bpermute entry bytes + issue W1-row loads into registers
//   for step t+1 -- all value-independent, overlaps step t's compute chain.
// CONS(stage): vals[] LDS reads (fresh), fmafs, DPP/DS folds, epilogue, write.
// ---------------------------------------------------------------------------
#define PREF(cnt_, node_, wb_, w_, m0_, m1_, svv) do {                        \
    uint32_t w0_ = (uint32_t)__builtin_amdgcn_readfirstlane((int)(svv));      \
    cnt_ = w0_ & 255; node_ = (w0_ >> 8) & 255;                               \
    if (cnt_ != 255) {                                                        \
        const float* Wp_ = W1 + (size_t)node_ * 4128 + jj;                    \
        _Pragma("unroll")                                                     \
        for (int k_ = 0; k_ < 7; ++k_) {                                      \
            if (k_ * 8 < cnt_) {                                              \
                wb_[k_] = (uint32_t)__builtin_amdgcn_ds_bpermute(             \
                    baddr + (k_ << 3), (int)(svv));                           \
                int d_ = (wb_[k_] >> sh2) & 255;                              \
                w_[k_] = *(const float4*)(Wp_ + (d_ << 5));                   \
            }                                                                 \
        }                                                                     \
    } else {                                                                  \
        uint32_t a_ = (uint32_t)__builtin_amdgcn_readlane((int)(svv), 2);     \
        uint32_t b_ = (uint32_t)__builtin_amdgcn_readlane((int)(svv), 3);     \
        uint32_t c_ = (uint32_t)__builtin_amdgcn_readlane((int)(svv), 4);     \
        uint32_t e_ = (uint32_t)__builtin_amdgcn_readlane((int)(svv), 5);     \
        m0_ = a_ | ((uint64_t)b_ << 32);                                      \
        m1_ = c_ | ((uint64_t)e_ << 32);                                      \
    }                                                                         \
} while (0)

#define CONS(cnt_, node_, wb_, w_, m0_, m1_) do {                             \
    const float* Wp_ = W1 + (size_t)node_ * 4128 + jj;                        \
    const float4 wx_  = *(const float4*)(Wp_ + 4096);                         \
    const float4 b1q_ = *(const float4*)(b1 + (node_ << 5) + jj);             \
    const float4 w2q_ = *(const float4*)(W2 + (node_ << 5) + jj);             \
    const float  xv_  = x[(b << 7) + node_];                                  \
    const float  b2v_ = b2[node_];                                            \
    float4 acc = make_float4(0.f, 0.f, 0.f, 0.f);                             \
    if (cnt_ != 255) {                                                        \
        _Pragma("unroll")                                                     \
        for (int k_ = 0; k_ < 7; ++k_) {                                      \
            if (k_ * 8 < cnt_) {                                              \
                int d_ = (wb_[k_] >> sh2) & 255;                              \
                float vv_ = vals[d_];                                         \
                acc.x = fmaf(vv_, w_[k_].x, acc.x);                           \
                acc.y = fmaf(vv_, w_[k_].y, acc.y);                           \
                acc.z = fmaf(vv_, w_[k_].z, acc.z);                           \
                acc.w = fmaf(vv_, w_[k_].w, acc.w);                           \
            }                                                                 \
        }                                                                     \
    } else {                                                                  \
        uint64_t mm0 = m0_, mm1 = m1_; int i_ = 0;                            \
        while (mm0) { int d_ = __builtin_ctzll(mm0); mm0 &= mm0 - 1;          \
            float vv_ = ((i_ & 7) == q) ? vals[d_] : 0.f;                     \
            const float4 wr_ = *(const float4*)(Wp_ + (d_ << 5));             \
            acc.x = fmaf(vv_, wr_.x, acc.x); acc.y = fmaf(vv_, wr_.y, acc.y); \
            acc.z = fmaf(vv_, wr_.z, acc.z); acc.w = fmaf(vv_, wr_.w, acc.w); \
            ++i_; }                                                           \
        while (mm1) { int d_ = 64 + __builtin_ctzll(mm1); mm1 &= mm1 - 1;     \
            float vv_ = ((i_ & 7) == q) ? vals[d_] : 0.f;                     \
            const float4 wr_ = *(const float4*)(Wp_ + (d_ << 5));             \
            acc.x = fmaf(vv_, wr_.x, acc.x); acc.y = fmaf(vv_, wr_.y, acc.y); \
            acc.z = fmaf(vv_, wr_.z, acc.z); acc.w = fmaf(vv_, wr_.w, acc.w); \
            ++i_; }                                                           \
    }                                                                         \
    acc.x += __shfl_xor(acc.x, 32); acc.y += __shfl_xor(acc.y, 32);           \
    acc.z += __shfl_xor(acc.z, 32); acc.w += __shfl_xor(acc.w, 32);           \
    acc.x += __shfl_xor(acc.x, 16); acc.y += __shfl_xor(acc.y, 16);           \
    acc.z += __shfl_xor(acc.z, 16); acc.w += __shfl_xor(acc.w, 16);           \
    acc.x = dppadd_xor8(acc.x); acc.y = dppadd_xor8(acc.y);                   \
    acc.z = dppadd_xor8(acc.z); acc.w = dppadd_xor8(acc.w);                   \
    acc.x = fmaf(xv_, wx_.x, acc.x) + b1q_.x;                                 \
    acc.y = fmaf(xv_, wx_.y, acc.y) + b1q_.y;                                 \
    acc.z = fmaf(xv_, wx_.z, acc.z) + b1q_.z;                                 \
    acc.w = fmaf(xv_, wx_.w, acc.w) + b1q_.w;                                 \
    float hx_ = fmaxf(acc.x, 0.01f * acc.x), hy_ = fmaxf(acc.y, 0.01f * acc.y); \
    float hz_ = fmaxf(acc.z, 0.01f * acc.z), hw_ = fmaxf(acc.w, 0.01f * acc.w); \
    float p_ = hx_ * w2q_.x + hy_ * w2q_.y + hz_ * w2q_.z + hw_ * w2q_.w;     \
    p_ = dppadd_xor1(p_);                                                     \
    p_ = dppadd_xor2(p_);                                                     \
    p_ = dppadd_xor4(p_);                                                     \
    const float outv_ = p_ + b2v_;                                            \
    if (node_ != dob) { if (lane == 0) vals[node_] = outv_; }                 \
} while (0)

__global__ __launch_bounds__(64, 4) void cond_mlp_list(
    const float* __restrict__ x, const float* __restrict__ u,
    const float* __restrict__ W1, const float* __restrict__ b1,
    const float* __restrict__ W2, const float* __restrict__ b2,
    const int* __restrict__ do_idxs, const uint32_t* __restrict__ lists,
    float* __restrict__ out)
{
    const int b = blockIdx.x;
    const int lane = threadIdx.x;
    const int jj = (lane & 7) << 2;               // h-quad base (float index)
    const int sh2 = lane & 24;                    // byte-in-word selector
    const int baddr = (2 + (lane >> 5)) << 2;     // bpermute byte addr base
    const int q = lane >> 3;                      // entry-group id 0..7
    const int wslot = lane & 15;

    __shared__ float vals[132];
    const int dob = do_idxs[b];
    const float ub = u[b];
    vals[lane]      = (lane == dob) ? ub : 0.f;
    vals[64 + lane] = (lane + 64 == dob) ? ub : 0.f;
    if (lane < 4) vals[128 + lane] = 0.f;

    const uint32_t* sp = lists + (size_t)b * BATCH_W;

    // pipeline state
    int Acnt, Anode, Bcnt, Bnode;
    uint32_t Awb[7], Bwb[7];
    float4 Aw[7], Bw[7];
    uint64_t Am0 = 0, Am1 = 0, Bm0 = 0, Bm1 = 0;

    uint32_t A_sv = sp[wslot];            // slot 0
    uint32_t B_sv = sp[SLOT_W + wslot];   // slot 1
    PREF(Acnt, Anode, Awb, Aw, Am0, Am1, A_sv);

    for (int t = 0; t < NN; t += 2) {
        const int t2 = (t + 2 < NN) ? t + 2 : NN - 1;
        const int t3 = (t + 3 < NN) ? t + 3 : NN - 1;
        const uint32_t C_sv = sp[t2 * SLOT_W + wslot];
        const uint32_t D_sv = sp[t3 * SLOT_W + wslot];

        PREF(Bcnt, Bnode, Bwb, Bw, Bm0, Bm1, B_sv);   // prefetch step t+1
        CONS(Acnt, Anode, Awb, Aw, Am0, Am1);         // compute step t
        PREF(Acnt, Anode, Awb, Aw, Am0, Am1, C_sv);   // prefetch step t+2
        CONS(Bcnt, Bnode, Bwb, Bw, Bm0, Bm1);         // compute step t+1
        B_sv = D_sv;
    }

    out[(b << 7) + lane]      = vals[lane];
    out[(b << 7) + 64 + lane] = vals[64 + lane];
}

// ---------------------------------------------------------------------------
// Fallback (R1 ballot kernel) if ws too small for the lists buffer.
// ---------------------------------------------------------------------------
__global__ __launch_bounds__(64) void cond_mlp_ballot(
    const float* __restrict__ x, const float* __restrict__ u,
    const float* __restrict__ W1, const float* __restrict__ b1,
    const float* __restrict__ W2, const float* __restrict__ b2,
    const int* __restrict__ order, const int* __restrict__ do_idxs,
    const ulonglong2* __restrict__ bitsT, float* __restrict__ out)
{
    const int b = blockIdx.x;
    const int lane = threadIdx.x;
    const int j = lane & 31;
    const int half = lane >> 5;

    __shared__ float2 ent[132];

    const float ub = u[b];
    const int dob = do_idxs[b];
    float out0 = (dob == lane) ? ub : 0.f;
    float out1 = (dob == lane + 64) ? ub : 0.f;

    const int* ord = order + b * NN;
    const ulonglong2* bb = bitsT + (size_t)b * NN;

    int node = ord[0];
    ulonglong2 bits = bb[node];

    for (int t = 0; t < NN; ++t) {
        const int node_n = (t < NN - 1) ? ord[t + 1] : 0;
        const ulonglong2 bits_n = bb[node_n];

        const float* Wn = W1 + (size_t)node * (NN + 1) * HH;
        const float w2v = W2[node * HH + j];
        const float b1v = b1[node * HH + j];
        const float xv  = x[b * NN + node];
        const float b2v = b2[node];

        unsigned long long bal0 = __ballot(out0 != 0.f) & bits.x;
        unsigned long long bal1 = __ballot(out1 != 0.f) & bits.y;
        const int c0 = __popcll(bal0);
        const int cnt = c0 + __popcll(bal1);
        const unsigned long long below = (1ull << lane) - 1;
        if (bal0 & (1ull << lane)) {
            int p = __popcll(bal0 & below);
            ent[p] = make_float2(out0, __int_as_float(lane));
        }
        if (bal1 & (1ull << lane)) {
            int p = c0 + __popcll(bal1 & below);
            ent[p] = make_float2(out1, __int_as_float(lane + 64));
        }
        const int cnt4 = (cnt + 3) & ~3;
        if (lane < cnt4 - cnt) ent[cnt + lane] = make_float2(0.f, __int_as_float(0));
        __syncthreads();

        float acc0 = 0.f, acc1 = 0.f;
        for (int k = 0; k < cnt4; k += 4) {
            float2 eA = ent[k + half];
            float2 eB = ent[k + 2 + half];
            acc0 += eA.x * Wn[__float_as_int(eA.y) * HH + j];
            acc1 += eB.x * Wn[__float_as_int(eB.y) * HH + j];
        }
        __syncthreads();

        float acc = acc0 + acc1;
        acc += __shfl_xor(acc, 32);
        acc += xv * Wn[NN * HH + j];
        acc += b1v;
        const float hv = (acc > 0.f) ? acc : 0.01f * acc;

        float p = hv * w2v;
        p += __shfl_xor(p, 16);
        p += __shfl_xor(p, 8);
        p += __shfl_xor(p, 4);
        p += __shfl_xor(p, 2);
        p += __shfl_xor(p, 1);
        const float outv = p + b2v;

        if (dob != node) {
            if (lane == (node & 63)) {
                if (node < 64) out0 = outv; else out1 = outv;
            }
        }
        node = node_n;
        bits = bits_n;
    }

    out[b * NN + lane] = out0;
    out[b * NN + 64 + lane] = out1;
}

extern "C" void kernel_launch(void* const* d_in, const int* in_sizes, int n_in,
                              void* d_out, int out_size, void* d_ws, size_t ws_size,
                              hipStream_t stream) {
    const float* x   = (const float*)d_in[0];
    const float* A   = (const float*)d_in[1];
    const float* u   = (const float*)d_in[2];
    const float* W1  = (const float*)d_in[3];
    const float* b1  = (const float*)d_in[4];
    const float* W2  = (const float*)d_in[5];
    const float* b2  = (const float*)d_in[6];
    const int* order = (const int*)d_in[7];
    const int* dox   = (const int*)d_in[8];

    unsigned long long* bitsW = (unsigned long long*)d_ws;        // 8 MB
    uint32_t* lists = (uint32_t*)((uint8_t*)d_ws + (size_t)8 * 1024 * 1024);
    const size_t need = (size_t)8 * 1024 * 1024 + (size_t)BB * NN * 68;  // ~44 MB

    pack_bits<<<(BB * 64) / 256, 256, 0, stream>>>(A, bitsW);
    if (ws_size >= need) {
        build_lists<<<BB / 4, 256, 0, stream>>>((const ulonglong2*)bitsW, order, dox, lists);
        cond_mlp_list<<<BB, 64, 0, stream>>>(x, u, W1, b1, W2, b2, dox, lists, (float*)d_out);
    } else {
        cond_mlp_ballot<<<BB, 64, 0, stream>>>(x, u, W1, b1, W2, b2, order, dox,
                                               (const ulonglong2*)bitsW, (float*)d_out);
    }
}